// Round 11
// baseline (2030.849 us; speedup 1.0000x reference)
//
#include <hip/hip_runtime.h>
#include <hip/hip_cooperative_groups.h>
namespace cg = cooperative_groups;

#define BB 4
#define TT 12
#define NN 10000
#define DD 2
#define EE 320000
#define HH 64
#define NPREDD 12
#define TD 24
#define NCHUNK 1250      // chunks of 8 nodes
#define NPC 8
#define CAP 512          // edges per chunk in LDS (mean 256, +16 sigma < 512; global fallback)

typedef __attribute__((ext_vector_type(8))) short bf16x8;
typedef __attribute__((ext_vector_type(4))) float f32x4;
typedef unsigned short u16;

__device__ __forceinline__ unsigned int pack2(float lo, float hi) {
    unsigned int r;
    asm("v_cvt_pk_bf16_f32 %0, %1, %2" : "=v"(r) : "v"(lo), "v"(hi));
    return r;
}
__device__ __forceinline__ float b2f(u16 u) {
    return __uint_as_float(((unsigned)u) << 16);
}

// ---------------- CSR build (keyed by dst; gather from src) ----------------
__global__ void hist_kernel(const int* __restrict__ dstv, int* __restrict__ deg) {
    int e = blockIdx.x*256 + threadIdx.x;
    if (e < EE) atomicAdd(&deg[dstv[e]], 1);
}

__global__ void scan_kernel(const int* __restrict__ deg, int* __restrict__ row_ptr,
                            int* __restrict__ cursor) {
    __shared__ int part[1024];
    int tid = threadIdx.x;
    const int CH = 10;
    int start = tid*CH;
    int s = 0;
    if (start < NN)
        for (int i=0;i<CH;i++) s += deg[start+i];
    part[tid] = s;
    __syncthreads();
    if (tid == 0) {
        int acc = 0;
        for (int i=0;i<1024;i++){ int v=part[i]; part[i]=acc; acc+=v; }
        row_ptr[NN] = acc;
    }
    __syncthreads();
    if (start < NN) {
        int acc = part[tid];
        for (int i=0;i<CH;i++){ int idx=start+i; row_ptr[idx]=acc; cursor[idx]=acc; acc+=deg[idx]; }
    }
}

__global__ void fill_kernel(const int* __restrict__ srcv, const int* __restrict__ dstv,
                            const float* __restrict__ ew, int* __restrict__ cursor,
                            int2* __restrict__ csr) {
    int e = blockIdx.x*256 + threadIdx.x;
    if (e < EE) {
        int d = dstv[e];
        int pos = atomicAdd(&cursor[d], 1);
        csr[pos] = make_int2(srcv[e], __float_as_int(ew[e]));
    }
}

// ---------------- x transpose: [B,T,N,D] -> [N][T*D][B] (batch fastest) ----------------
__global__ void transpose_x(const float* __restrict__ x, float* __restrict__ xTb) {
    int idx = blockIdx.x*256 + threadIdx.x;
    if (idx >= BB*TT*NN*DD) return;
    int d = idx & 1;
    int n = (idx >> 1) % NN;
    int t = (idx / (NN*DD)) % TT;
    int b = idx / (TT*NN*DD);
    xTb[((size_t)n*TD + (t*DD + d))*BB + b] = x[idx];
}

// ---------------- weight fragments in MFMA B-operand order ----------------
__global__ void prep_wfrag(const float* __restrict__ W0, const float* __restrict__ W1,
                           unsigned short* __restrict__ wf0, unsigned short* __restrict__ wf1) {
    int tid = blockIdx.x*256 + threadIdx.x;
    if (tid >= 2560) return;
    int layer = tid / 1280;
    int r = tid % 1280;
    int lane = r & 63;
    int ctkt = r >> 6;
    int ct = ctkt / 5, kt = ctkt % 5;
    int c = ct*16 + (lane & 15);
    int k0 = kt*32 + (lane >> 4)*8;
    unsigned short* dst = (layer ? wf1 : wf0) + r*8;
    for (int j=0;j<8;j++) {
        int k = k0 + j;
        float w = 0.f;
        if (layer == 0) {
            if (k < 64)        w = W0[(2+k)*64 + c];
            else if (k < 128)  w = W0[4224 + (2+(k-64))*64 + c];
            else if (k == 128) w = W0[c];
            else if (k == 129) w = W0[64 + c];
            else if (k == 130) w = W0[4224 + c];
            else if (k == 131) w = W0[4224 + 64 + c];
        } else {
            if (k < 64)        w = W1[k*64 + c] + W1[(k+64)*64 + c];
            else if (k < 128)  w = W1[8192 + (k-64)*64 + c] + W1[8192 + k*64 + c];
        }
        unsigned int u = __float_as_uint(w);
        unsigned int rnd = (u + 0x7fffu + ((u >> 16) & 1u)) >> 16;   // RNE
        dst[j] = (unsigned short)rnd;
    }
}

// ---------------- persistent cooperative kernel: 24 phases + output tail ----------------
// h layout [N][B][64] bf16 (node row = 512 B). 512 thr = 8 waves; chunk = 8 nodes;
// wave w owns node n0+w (all 4 batches). lane: bq=lane>>4 (batch), cq=lane&15 (ch quad).
// Gather: one edge = one full-wave 512B coalesced load, 16 in flight (unroll 16).
// Phase 0 (t=0,L0): h==0, so the gather slot computes AX = A@x (all 24 td x 4 b) instead.
// Normal (write-back) stores; grid.sync() between phases provides cross-XCD visibility.
__global__ __launch_bounds__(512, 6)
void persist2(u16* __restrict__ hA, u16* __restrict__ hB,
              const float* __restrict__ x, const float* __restrict__ xTb,
              float* __restrict__ AXb,
              const unsigned short* __restrict__ wf0, const unsigned short* __restrict__ wf1,
              const float* __restrict__ b0, const float* __restrict__ b1,
              const int* __restrict__ row_ptr, const int2* __restrict__ csr,
              const float* __restrict__ Wp, const float* __restrict__ bp,
              float* __restrict__ outp)
{
    __shared__ int2 sIdx[CAP];              // 4 KB: chunk's csr segment (raw src, w)
    __shared__ unsigned short sA[32*168];   // 10.5 KB: bf16 MFMA A tile (32 rows x K=160+pad)

    cg::grid_group gg = cg::this_grid();

    const int tid = threadIdx.x;
    const int wave = tid >> 6, lane = tid & 63;
    const int bq = lane >> 4, cq = lane & 15;
    const int G = (int)gridDim.x;
    const int bid = (int)blockIdx.x;
    const int laneoff = (bq*HH + cq*4)*2;   // byte offset within 512B node row
    const int ct = wave & 3, mt = wave >> 2;

    for (int ph = 0; ph < 2*TT; ++ph) {
        const int t = ph >> 1;
        const int L0 = !(ph & 1);
        const u16* hin  = L0 ? hA : hB;
        u16*       hout = L0 ? hB : hA;
        const unsigned short* wf = L0 ? wf0 : wf1;
        const float* bias = L0 ? b0 : b1;

        for (int ck = bid; ck < NCHUNK; ck += G) {
            const int n0 = ck * NPC;
            const int estart = row_ptr[n0];
            const int cnt = row_ptr[n0 + NPC] - estart;
            const int lim = cnt > CAP ? CAP : cnt;
            {
                int2 v = make_int2(0, 0);
                if (tid < lim) v = csr[estart + tid];
                sIdx[tid] = v;              // CAP==512==blockDim
            }
            const int n = n0 + wave;
            const int rowL = wave*4 + bq;
            const int eb = row_ptr[n] - estart;
            const int ee = row_ptr[n+1] - estart;

            if (ph == 0) {
                // ---- zero-phase: AX gather (h==0) ----
                __syncthreads();            // sIdx staged
                float2 axacc = {0.f, 0.f};
                if (cnt <= CAP) {
                    for (int e = eb; e < ee; e += 8) {
                        #pragma unroll
                        for (int u = 0; u < 8; ++u) {
                            int idx = e + u;
                            int2 cw = sIdx[idx & (CAP-1)];
                            float w = (idx < ee) ? __int_as_float(cw.y) : 0.f;
                            float2 v = *(const float2*)((const char*)xTb + (size_t)cw.x*(TD*BB*4) + lane*8);
                            axacc.x = fmaf(w, v.x, axacc.x);
                            axacc.y = fmaf(w, v.y, axacc.y);
                        }
                    }
                } else {
                    for (int e = eb; e < ee; e += 8) {
                        #pragma unroll
                        for (int u = 0; u < 8; ++u) {
                            int idx = e + u;
                            int2 cw = (idx < ee) ? csr[estart + idx] : make_int2(0,0);
                            float w = (idx < ee) ? __int_as_float(cw.y) : 0.f;
                            float2 v = *(const float2*)((const char*)xTb + (size_t)cw.x*(TD*BB*4) + lane*8);
                            axacc.x = fmaf(w, v.x, axacc.x);
                            axacc.y = fmaf(w, v.y, axacc.y);
                        }
                    }
                }
                if (lane < TD*BB/2)
                    *(float2*)(AXb + (size_t)n*(TD*BB) + lane*2) = axacc;
                // zero h and A@h regions of sA
                *(ushort4*)&sA[rowL*168 + cq*4] = make_ushort4(0,0,0,0);
                *(uint2*)&sA[rowL*168 + 64 + cq*4] = make_uint2(0u, 0u);
                __syncthreads();            // drain AXb stores before readback for extras
            } else {
                // ---- normal phase: h gather ----
                ushort4 hv = *(const ushort4*)((const char*)hin + ((size_t)n << 9) + laneoff);
                __syncthreads();            // sIdx staged
                float4 acc = {0.f,0.f,0.f,0.f};
                if (cnt <= CAP) {
                    for (int e = eb; e < ee; e += 16) {
                        #pragma unroll
                        for (int u = 0; u < 16; ++u) {
                            int idx = e + u;
                            int2 cw = sIdx[idx & (CAP-1)];
                            float w = (idx < ee) ? __int_as_float(cw.y) : 0.f;
                            ushort4 v = *(const ushort4*)((const char*)hin + ((size_t)cw.x << 9) + laneoff);
                            acc.x = fmaf(w, b2f(v.x), acc.x);
                            acc.y = fmaf(w, b2f(v.y), acc.y);
                            acc.z = fmaf(w, b2f(v.z), acc.z);
                            acc.w = fmaf(w, b2f(v.w), acc.w);
                        }
                    }
                } else {
                    for (int e = eb; e < ee; e += 16) {
                        #pragma unroll
                        for (int u = 0; u < 16; ++u) {
                            int idx = e + u;
                            int2 cw = (idx < ee) ? csr[estart + idx] : make_int2(0,0);
                            float w = (idx < ee) ? __int_as_float(cw.y) : 0.f;
                            ushort4 v = *(const ushort4*)((const char*)hin + ((size_t)cw.x << 9) + laneoff);
                            acc.x = fmaf(w, b2f(v.x), acc.x);
                            acc.y = fmaf(w, b2f(v.y), acc.y);
                            acc.z = fmaf(w, b2f(v.z), acc.z);
                            acc.w = fmaf(w, b2f(v.w), acc.w);
                        }
                    }
                }
                *(ushort4*)&sA[rowL*168 + cq*4] = hv;
                uint2 pk; pk.x = pack2(acc.x, acc.y); pk.y = pack2(acc.z, acc.w);
                *(uint2*)&sA[rowL*168 + 64 + cq*4] = pk;
            }

            // extras (k=128..131) + zero tail (k=132..159)
            if (cq == 0) {
                uint2 pk;
                if (L0) {
                    const float2 xv = *(const float2*)(x + (((size_t)bq*TT + t)*NN + n)*DD);
                    float ax0 = AXb[(size_t)n*(TD*BB) + (2*t)*BB + bq];
                    float ax1 = AXb[(size_t)n*(TD*BB) + (2*t+1)*BB + bq];
                    pk.x = pack2(xv.x, xv.y); pk.y = pack2(ax0, ax1);
                } else { pk.x = 0u; pk.y = 0u; }
                *(uint2*)&sA[rowL*168 + 128] = pk;
            } else if (cq < 8) {
                *(uint2*)&sA[rowL*168 + 132 + (cq-1)*4] = make_uint2(0u, 0u);
            }

            // B fragments + bias (loaded late to keep gather register pressure low)
            const bf16x8* wfv = (const bf16x8*)wf;
            bf16x8 bfr[5];
            #pragma unroll
            for (int kt = 0; kt < 5; ++kt) bfr[kt] = wfv[(ct*5 + kt)*64 + lane];
            float bv = bias[ct*16 + cq];

            __syncthreads();                // sA complete

            // MFMA: C-tile (mt, ct); A row = lane&15, k = (lane>>4)*8 + j
            f32x4 dacc = {0.f,0.f,0.f,0.f};
            #pragma unroll
            for (int kt = 0; kt < 5; ++kt) {
                bf16x8 a = *(const bf16x8*)&sA[(mt*16 + cq)*168 + kt*32 + bq*8];
                dacc = __builtin_amdgcn_mfma_f32_16x16x32_bf16(a, bfr[kt], dacc, 0, 0, 0);
            }
            #pragma unroll
            for (int i2 = 0; i2 < 4; ++i2) {
                int r = mt*16 + bq*4 + i2;       // C/D: row=(lane>>4)*4+reg, col=lane&15
                int node = n0 + (r >> 2), b = r & 3;
                float vv = fmaxf(dacc[i2] + bv, 0.f);
                unsigned pk = pack2(vv, vv);
                hout[((size_t)node*BB + b)*HH + ct*16 + cq] = (u16)pk;
            }
            __syncthreads();                // protect sIdx/sA restage next chunk
        } // chunks

        if (ph != 2*TT - 1) gg.sync();
    } // phases

    // ---- output tail: each block projects its own chunks' rows (written above) ----
    for (int ck = bid; ck < NCHUNK; ck += G) {
        int n0 = ck * NPC;
        for (int r = wave; r < NPC*BB; r += 8) {
            int n = n0 + (r >> 2), b = r & 3;
            float v = b2f(hA[((size_t)n*BB + b)*HH + lane]) * Wp[lane];
            for (int off = 32; off; off >>= 1) v += __shfl_down(v, off);
            v = __shfl(v, 0) + bp[0];
            if (lane < NPREDD) outp[((size_t)b*NPREDD + lane)*NN + n] = v;
        }
    }
}

extern "C" void kernel_launch(void* const* d_in, const int* in_sizes, int n_in,
                              void* d_out, int out_size, void* d_ws, size_t ws_size,
                              hipStream_t stream) {
    const float* x   = (const float*)d_in[0];
    const int*   ei  = (const int*)d_in[1];
    const float* ew  = (const float*)d_in[2];
    const float* W0  = (const float*)d_in[3];
    const float* b0  = (const float*)d_in[4];
    const float* W1  = (const float*)d_in[5];
    const float* b1  = (const float*)d_in[6];
    const float* Wp  = (const float*)d_in[7];
    const float* bp  = (const float*)d_in[8];
    float* outp = (float*)d_out;

    char* ws = (char*)d_ws;
    size_t off = 0;
    auto alloc = [&](size_t bytes) { void* p = ws + off; off = (off + bytes + 255) & ~(size_t)255; return p; };
    u16* h      = (u16*)alloc((size_t)NN*BB*HH*2);
    u16* h1     = (u16*)alloc((size_t)NN*BB*HH*2);
    float* xTb  = (float*)alloc(((size_t)NN*TD*BB + 128)*4);   // +pad: lanes 48-63 overread
    float* AXb  = (float*)alloc((size_t)NN*TD*BB*4);
    unsigned short* wf0 = (unsigned short*)alloc(1280*8*2);
    unsigned short* wf1 = (unsigned short*)alloc(1280*8*2);
    int2*  csr  = (int2*)alloc(((size_t)EE + 16)*8);
    int* row_ptr= (int*)alloc((NN+1)*4);
    int* deg    = (int*)alloc(NN*4);
    int* cursor = (int*)alloc(NN*4);

    const int* srcv = ei;
    const int* dstv = ei + EE;

    hipMemsetAsync(deg, 0, NN*4, stream);

    hist_kernel<<<(EE+255)/256, 256, 0, stream>>>(dstv, deg);
    scan_kernel<<<1, 1024, 0, stream>>>(deg, row_ptr, cursor);
    fill_kernel<<<(EE+255)/256, 256, 0, stream>>>(srcv, dstv, ew, cursor, csr);
    transpose_x<<<(BB*TT*NN*DD+255)/256, 256, 0, stream>>>(x, xTb);
    prep_wfrag<<<10, 256, 0, stream>>>(W0, W1, wf0, wf1);

    // co-residency-safe grid: balanced divisors of ~1250
    int occ = 0;
    hipOccupancyMaxActiveBlocksPerMultiprocessor(&occ, persist2, 512, 0);
    int cap = occ * 256;
    int Gr = (cap >= 625) ? 625 : (cap >= 313) ? 313 : (cap >= 157) ? 157 : 79;

    void* kargs[] = { (void*)&h, (void*)&h1, (void*)&x, (void*)&xTb, (void*)&AXb,
                      (void*)&wf0, (void*)&wf1, (void*)&b0, (void*)&b1,
                      (void*)&row_ptr, (void*)&csr, (void*)&Wp, (void*)&bp, (void*)&outp };
    hipLaunchCooperativeKernel((void*)persist2, dim3(Gr), dim3(512), kargs, 0, stream);
}

// Round 12
// 677.780 us; speedup vs baseline: 2.9963x; 2.9963x over previous
//
#include <hip/hip_runtime.h>

#define BB 4
#define TT 12
#define NN 10000
#define DD 2
#define EE 320000
#define HH 64
#define NPREDD 12
#define TD 24
#define NPC 8            // nodes per block
#define CAP 512          // edges per chunk in LDS (mean 256; global fallback beyond)

typedef __attribute__((ext_vector_type(8))) short bf16x8;
typedef __attribute__((ext_vector_type(8))) unsigned short u16x8;
typedef __attribute__((ext_vector_type(4))) float f32x4;
typedef unsigned short u16;

__device__ __forceinline__ unsigned int pack2(float lo, float hi) {
    unsigned int r;
    asm("v_cvt_pk_bf16_f32 %0, %1, %2" : "=v"(r) : "v"(lo), "v"(hi));
    return r;
}
__device__ __forceinline__ float b2f(u16 u) {
    return __uint_as_float(((unsigned)u) << 16);
}

// ---------------- CSR build (keyed by dst; gather from src) ----------------
__global__ void hist_kernel(const int* __restrict__ dstv, int* __restrict__ deg) {
    int e = blockIdx.x*256 + threadIdx.x;
    if (e < EE) atomicAdd(&deg[dstv[e]], 1);
}

__global__ void scan_kernel(const int* __restrict__ deg, int* __restrict__ row_ptr,
                            int* __restrict__ cursor) {
    __shared__ int part[1024];
    int tid = threadIdx.x;
    const int CH = 10;
    int start = tid*CH;
    int s = 0;
    if (start < NN)
        for (int i=0;i<CH;i++) s += deg[start+i];
    part[tid] = s;
    __syncthreads();
    if (tid == 0) {
        int acc = 0;
        for (int i=0;i<1024;i++){ int v=part[i]; part[i]=acc; acc+=v; }
        row_ptr[NN] = acc;
    }
    __syncthreads();
    if (start < NN) {
        int acc = part[tid];
        for (int i=0;i<CH;i++){ int idx=start+i; row_ptr[idx]=acc; cursor[idx]=acc; acc+=deg[idx]; }
    }
}

__global__ void fill_kernel(const int* __restrict__ srcv, const int* __restrict__ dstv,
                            const float* __restrict__ ew, int* __restrict__ cursor,
                            int2* __restrict__ csr) {
    int e = blockIdx.x*256 + threadIdx.x;
    if (e < EE) {
        int d = dstv[e];
        int pos = atomicAdd(&cursor[d], 1);
        csr[pos] = make_int2(srcv[e], __float_as_int(ew[e]));
    }
}

// ---------------- x transpose: [B,T,N,D] -> [N][T*D][B] (batch fastest) ----------------
__global__ void transpose_x(const float* __restrict__ x, float* __restrict__ xTb) {
    int idx = blockIdx.x*256 + threadIdx.x;
    if (idx >= BB*TT*NN*DD) return;
    int d = idx & 1;
    int n = (idx >> 1) % NN;
    int t = (idx / (NN*DD)) % TT;
    int b = idx / (TT*NN*DD);
    xTb[((size_t)n*TD + (t*DD + d))*BB + b] = x[idx];
}

// ---------------- weight fragments in MFMA B-operand order ----------------
__global__ void prep_wfrag(const float* __restrict__ W0, const float* __restrict__ W1,
                           unsigned short* __restrict__ wf0, unsigned short* __restrict__ wf1) {
    int tid = blockIdx.x*256 + threadIdx.x;
    if (tid >= 2560) return;
    int layer = tid / 1280;
    int r = tid % 1280;
    int lane = r & 63;
    int ctkt = r >> 6;
    int ct = ctkt / 5, kt = ctkt % 5;
    int c = ct*16 + (lane & 15);
    int k0 = kt*32 + (lane >> 4)*8;
    unsigned short* dst = (layer ? wf1 : wf0) + r*8;
    for (int j=0;j<8;j++) {
        int k = k0 + j;
        float w = 0.f;
        if (layer == 0) {
            if (k < 64)        w = W0[(2+k)*64 + c];
            else if (k < 128)  w = W0[4224 + (2+(k-64))*64 + c];
            else if (k == 128) w = W0[c];
            else if (k == 129) w = W0[64 + c];
            else if (k == 130) w = W0[4224 + c];
            else if (k == 131) w = W0[4224 + 64 + c];
        } else {
            if (k < 64)        w = W1[k*64 + c] + W1[(k+64)*64 + c];
            else if (k < 128)  w = W1[8192 + (k-64)*64 + c] + W1[8192 + k*64 + c];
        }
        unsigned int u = __float_as_uint(w);
        unsigned int rnd = (u + 0x7fffu + ((u >> 16) & 1u)) >> 16;   // RNE
        dst[j] = (unsigned short)rnd;
    }
}

// ---------------- fused layer ----------------
// h layout [N][B][64] bf16 (node row = 512 B). 512 thr = 8 waves; 8 nodes/block;
// wave w owns node n0+w (all 4 batches).
// Gather lanes: half=lane>>5 (edge parity), sub=lane&31 -> (b=sub>>3, ch8=sub&7).
// One pair of edges = two 16B ushort8 loads per lane (1 KB per wave-instr-pair);
// 8 pairs (16 edges) in flight per trip. shfl_xor(32) folds the halves.
// Z=1 (t=0,L0): h==0 -> gather slot computes AX = A@x, writes AXb, feeds own extras.
// F=1 (final): projects out = h@Wp + bp for own rows after the store.
template<int L0, int Z, int F>
__global__ __launch_bounds__(512, 8)
void layer_kernel(const u16* __restrict__ h_in,
                  u16* __restrict__ h_out,
                  const float* __restrict__ x,
                  const float* __restrict__ xTb,
                  float* __restrict__ AXb,
                  const unsigned short* __restrict__ wf,
                  const float* __restrict__ bias,
                  const int* __restrict__ row_ptr,
                  const int2* __restrict__ csr,
                  const float* __restrict__ Wp,
                  const float* __restrict__ bp,
                  float* __restrict__ outp,
                  int t)
{
    __shared__ int2 sIdx[CAP];              // 4 KB: (src<<9 | raw src for Z, weight)
    __shared__ unsigned short sA[32*168];   // 10.5 KB bf16 A tile (32 rows x K<=160)

    const int tid = threadIdx.x;
    const int wave = tid >> 6, lane = tid & 63;
    const int half = lane >> 5, sub = lane & 31;
    const int bq = lane >> 4, cq = lane & 15;

    const int n0 = blockIdx.x * NPC;        // 1250*8 = 10000
    const int estart = row_ptr[n0];
    const int cnt = row_ptr[n0 + NPC] - estart;
    const int lim = cnt > CAP ? CAP : cnt;
    {
        int2 v = make_int2(0, 0);
        if (tid < lim) {
            int2 cw = csr[estart + tid];
            v = make_int2(Z ? cw.x : (cw.x << 9), cw.y);
        }
        sIdx[tid] = v;
    }

    const int n = n0 + wave;
    const int eb = row_ptr[n] - estart;
    const int ee = row_ptr[n+1] - estart;
    const int rowG = wave*4 + (sub >> 3);   // row for gather-lane writes
    const int ch8 = sub & 7;

    float ax0 = 0.f, ax1 = 0.f;

    if (Z) {
        __syncthreads();                    // sIdx staged
        // AX gather: 1 edge per wave-load (lanes<48 active, float2 each)
        float2 axacc = {0.f, 0.f};
        if (cnt <= CAP) {
            for (int e = eb; e < ee; e += 16) {
                #pragma unroll
                for (int u = 0; u < 16; ++u) {
                    int idx = e + u;
                    int2 ow = sIdx[idx & (CAP-1)];
                    float w = (idx < ee) ? __int_as_float(ow.y) : 0.f;
                    if (lane < 48) {
                        float2 v = *(const float2*)(xTb + (size_t)ow.x*(TD*BB) + lane*2);
                        axacc.x = fmaf(w, v.x, axacc.x);
                        axacc.y = fmaf(w, v.y, axacc.y);
                    }
                }
            }
        } else {
            for (int e = eb; e < ee; e += 16) {
                #pragma unroll
                for (int u = 0; u < 16; ++u) {
                    int idx = e + u;
                    int2 cw = (idx < ee) ? csr[estart + idx] : make_int2(0,0);
                    float w = (idx < ee) ? __int_as_float(cw.y) : 0.f;
                    if (lane < 48) {
                        float2 v = *(const float2*)(xTb + (size_t)cw.x*(TD*BB) + lane*2);
                        axacc.x = fmaf(w, v.x, axacc.x);
                        axacc.y = fmaf(w, v.y, axacc.y);
                    }
                }
            }
        }
        if (lane < 48)
            *(float2*)(AXb + (size_t)n*(TD*BB) + lane*2) = axacc;
        // extras need AX[n,0,bq], AX[n,1,bq]: elements live in lanes 0..3
        float s0x = __shfl(axacc.x, bq >> 1);
        float s0y = __shfl(axacc.y, bq >> 1);
        float s1x = __shfl(axacc.x, 2 + (bq >> 1));
        float s1y = __shfl(axacc.y, 2 + (bq >> 1));
        ax0 = (bq & 1) ? s0y : s0x;
        ax1 = (bq & 1) ? s1y : s1x;
        // h and A@h regions are zero
        if (half == 0) {
            *(uint4*)&sA[rowG*168 + ch8*8]      = make_uint4(0u,0u,0u,0u);
            *(uint4*)&sA[rowG*168 + 64 + ch8*8] = make_uint4(0u,0u,0u,0u);
        }
    } else {
        // direct term: 16B per lane (lanes<32), issued before the barrier
        u16x8 hv;
        if (half == 0)
            hv = *(const u16x8*)((const char*)h_in + ((size_t)n << 9) + sub*16);
        __syncthreads();                    // sIdx staged
        float acc[8];
        #pragma unroll
        for (int j=0;j<8;j++) acc[j] = 0.f;
        if (cnt <= CAP) {
            for (int e = eb; e < ee; e += 16) {
                #pragma unroll
                for (int u = 0; u < 8; ++u) {
                    int idx = e + 2*u + half;
                    int2 ow = sIdx[idx & (CAP-1)];
                    float w = (idx < ee) ? __int_as_float(ow.y) : 0.f;
                    u16x8 v = *(const u16x8*)((const char*)h_in + ow.x + sub*16);
                    #pragma unroll
                    for (int j=0;j<8;j++) acc[j] = fmaf(w, b2f(v[j]), acc[j]);
                }
            }
        } else {
            for (int e = eb; e < ee; e += 16) {
                #pragma unroll
                for (int u = 0; u < 8; ++u) {
                    int idx = e + 2*u + half;
                    int2 cw = (idx < ee) ? csr[estart + idx] : make_int2(0,0);
                    float w = (idx < ee) ? __int_as_float(cw.y) : 0.f;
                    u16x8 v = *(const u16x8*)((const char*)h_in + ((size_t)cw.x << 9) + sub*16);
                    #pragma unroll
                    for (int j=0;j<8;j++) acc[j] = fmaf(w, b2f(v[j]), acc[j]);
                }
            }
        }
        #pragma unroll
        for (int j=0;j<8;j++) acc[j] += __shfl_xor(acc[j], 32);
        if (half == 0) {
            *(u16x8*)&sA[rowG*168 + ch8*8] = hv;
            uint4 pk;
            pk.x = pack2(acc[0], acc[1]); pk.y = pack2(acc[2], acc[3]);
            pk.z = pack2(acc[4], acc[5]); pk.w = pack2(acc[6], acc[7]);
            *(uint4*)&sA[rowG*168 + 64 + ch8*8] = pk;
        }
    }

    // extras (k=128..131) + zero tail (k=132..159); rowL = wave*4 + bq
    {
        int rowL = wave*4 + bq;
        if (cq == 0) {
            uint2 pk;
            if (L0) {
                const float2 xv = *(const float2*)(x + (((size_t)bq*TT + t)*NN + n)*DD);
                float a0, a1;
                if (Z) { a0 = ax0; a1 = ax1; }
                else {
                    a0 = AXb[(size_t)n*(TD*BB) + (2*t)*BB + bq];
                    a1 = AXb[(size_t)n*(TD*BB) + (2*t+1)*BB + bq];
                }
                pk.x = pack2(xv.x, xv.y); pk.y = pack2(a0, a1);
            } else { pk.x = 0u; pk.y = 0u; }
            *(uint2*)&sA[rowL*168 + 128] = pk;
        } else if (cq < 8) {
            *(uint2*)&sA[rowL*168 + 132 + (cq-1)*4] = make_uint2(0u, 0u);
        }
    }

    // B fragments + bias (loaded late to keep gather register pressure low)
    const int ct = wave & 3, mt = wave >> 2;
    const bf16x8* wfv = (const bf16x8*)wf;
    bf16x8 bfr[5];
    #pragma unroll
    for (int kt = 0; kt < 5; ++kt) bfr[kt] = wfv[(ct*5 + kt)*64 + lane];
    float bv = bias[ct*16 + cq];

    __syncthreads();                        // sA complete

    f32x4 dacc = {0.f,0.f,0.f,0.f};
    #pragma unroll
    for (int kt = 0; kt < 5; ++kt) {
        bf16x8 a = *(const bf16x8*)&sA[(mt*16 + cq)*168 + kt*32 + bq*8];
        dacc = __builtin_amdgcn_mfma_f32_16x16x32_bf16(a, bfr[kt], dacc, 0, 0, 0);
    }
    #pragma unroll
    for (int i2 = 0; i2 < 4; ++i2) {
        int r = mt*16 + bq*4 + i2;          // C/D: row=(lane>>4)*4+reg, col=lane&15
        int node = n0 + (r >> 2), b = r & 3;
        float vv = fmaxf(dacc[i2] + bv, 0.f);
        unsigned pk = pack2(vv, vv);
        h_out[((size_t)node*BB + b)*HH + ct*16 + cq] = (u16)pk;
    }

    if (F) {
        __syncthreads();                    // own stores drained (syncthreads waits vmcnt)
        for (int r = wave; r < NPC*BB; r += 8) {
            int n2 = n0 + (r >> 2), b2 = r & 3;
            float v = b2f(h_out[((size_t)n2*BB + b2)*HH + lane]) * Wp[lane];
            for (int off = 32; off; off >>= 1) v += __shfl_down(v, off);
            v = __shfl(v, 0) + bp[0];
            if (lane < NPREDD) outp[((size_t)b2*NPREDD + lane)*NN + n2] = v;
        }
    }
}

extern "C" void kernel_launch(void* const* d_in, const int* in_sizes, int n_in,
                              void* d_out, int out_size, void* d_ws, size_t ws_size,
                              hipStream_t stream) {
    const float* x   = (const float*)d_in[0];
    const int*   ei  = (const int*)d_in[1];
    const float* ew  = (const float*)d_in[2];
    const float* W0  = (const float*)d_in[3];
    const float* b0  = (const float*)d_in[4];
    const float* W1  = (const float*)d_in[5];
    const float* b1  = (const float*)d_in[6];
    const float* Wp  = (const float*)d_in[7];
    const float* bp  = (const float*)d_in[8];
    float* outp = (float*)d_out;

    char* ws = (char*)d_ws;
    size_t off = 0;
    auto alloc = [&](size_t bytes) { void* p = ws + off; off = (off + bytes + 255) & ~(size_t)255; return p; };
    u16* h      = (u16*)alloc((size_t)NN*BB*HH*2);
    u16* h1     = (u16*)alloc((size_t)NN*BB*HH*2);
    float* xTb  = (float*)alloc(((size_t)NN*TD*BB + 128)*4);
    float* AXb  = (float*)alloc((size_t)NN*TD*BB*4);
    unsigned short* wf0 = (unsigned short*)alloc(1280*8*2);
    unsigned short* wf1 = (unsigned short*)alloc(1280*8*2);
    int2*  csr  = (int2*)alloc(((size_t)EE + 16)*8);
    int* row_ptr= (int*)alloc((NN+1)*4);
    int* deg    = (int*)alloc(NN*4);
    int* cursor = (int*)alloc(NN*4);

    const int* srcv = ei;
    const int* dstv = ei + EE;

    hipMemsetAsync(deg, 0, NN*4, stream);

    hist_kernel<<<(EE+255)/256, 256, 0, stream>>>(dstv, deg);
    scan_kernel<<<1, 1024, 0, stream>>>(deg, row_ptr, cursor);
    fill_kernel<<<(EE+255)/256, 256, 0, stream>>>(srcv, dstv, ew, cursor, csr);
    transpose_x<<<(BB*TT*NN*DD+255)/256, 256, 0, stream>>>(x, xTb);
    prep_wfrag<<<10, 256, 0, stream>>>(W0, W1, wf0, wf1);

    const int grid = 1250;
    // t=0: layer0 has h==0 -> Z variant computes AX in the free gather slot
    layer_kernel<1,1,0><<<grid, 512, 0, stream>>>(h,  h1, x, xTb, AXb, wf0, b0, row_ptr, csr, Wp, bp, outp, 0);
    layer_kernel<0,0,0><<<grid, 512, 0, stream>>>(h1, h,  x, xTb, AXb, wf1, b1, row_ptr, csr, Wp, bp, outp, 0);
    for (int t=1; t<TT; ++t) {
        layer_kernel<1,0,0><<<grid, 512, 0, stream>>>(h,  h1, x, xTb, AXb, wf0, b0, row_ptr, csr, Wp, bp, outp, t);
        if (t < TT-1)
            layer_kernel<0,0,0><<<grid, 512, 0, stream>>>(h1, h, x, xTb, AXb, wf1, b1, row_ptr, csr, Wp, bp, outp, 0);
        else
            layer_kernel<0,0,1><<<grid, 512, 0, stream>>>(h1, h, x, xTb, AXb, wf1, b1, row_ptr, csr, Wp, bp, outp, 0);
    }
}